// Round 3
// baseline (117.436 us; speedup 1.0000x reference)
//
#include <hip/hip_runtime.h>

#define B_TOT 16384
#define NQ 7
#define H 64
#define MD 28

// ws layout (floats)
#define OFF_X  0
#define OFF_XD (B_TOT*MD)
#define OFF_S0 (2*B_TOT*MD)
#define OFF_S1 (OFF_S0 + B_TOT*H)
#define OFF_SV (OFF_S1 + B_TOT*H)
#define OFF_MI (OFF_SV + B_TOT*MD)
#define OFF_RP (OFF_MI + B_TOT*MD)
// total = B_TOT*(28+28+64+64+28+28+7) = B_TOT*247 floats ~= 15.4 MiB

#define OIDX(hi,lo) ((hi)*((hi)-1)/2 + (lo))

__device__ __forceinline__ float lane_bcast(float v, int k) {
    return __int_as_float(__builtin_amdgcn_readlane(__float_as_int(v), k));
}
__device__ __forceinline__ float sigmoid_f(float a) {
    return 1.0f / (1.0f + __expf(-a));
}
__device__ __forceinline__ float softplus_f(float a) {
    return fmaxf(a, 0.0f) + log1pf(__expf(-fabsf(a)));
}

// ---------------- K1: M-net forward + directional derivative ----------------
__global__ __launch_bounds__(256) void k1_mnet(
    const float* __restrict__ q, const float* __restrict__ dq,
    const float* __restrict__ WM0, const float* __restrict__ bM0,
    const float* __restrict__ WM1, const float* __restrict__ bM1,
    const float* __restrict__ WM2, const float* __restrict__ bM2,
    float* __restrict__ ws)
{
    __shared__ float W0s[H*NQ];
    __shared__ float W1s[H*65];
    __shared__ float W2s[MD*65];
    __shared__ float b0s[H], b1s[H], b2s[MD];
    const int tid = threadIdx.x;
    for (int t = tid; t < H*NQ; t += 256) W0s[t] = WM0[t];
    for (int t = tid; t < H*H;  t += 256) W1s[(t>>6)*65 + (t&63)] = WM1[t];
    for (int t = tid; t < MD*H; t += 256) W2s[(t>>6)*65 + (t&63)] = WM2[t];
    if (tid < H) { b0s[tid] = bM0[tid]; b1s[tid] = bM1[tid]; }
    else if (tid < H+MD) b2s[tid-H] = bM2[tid-H];
    __syncthreads();

    const int lane = tid & 63;
    const int b = (blockIdx.x<<2) + (tid>>6);

    float qv[NQ], dqv[NQ];
    #pragma unroll
    for (int d=0; d<NQ; d++){ qv[d]=q[b*NQ+d]; dqv[d]=dq[b*NQ+d]; }

    // layer 0
    float a0 = b0s[lane], j0d = 0.0f;
    #pragma unroll
    for (int d=0; d<NQ; d++){ float w = W0s[lane*NQ+d]; a0 = fmaf(w,qv[d],a0); j0d = fmaf(w,dqv[d],j0d); }
    float z0 = softplus_f(a0), s0 = sigmoid_f(a0);
    float j0 = s0 * j0d;
    ws[OFF_S0 + b*H + lane] = s0;

    // layer 1
    float a1 = b1s[lane], j1a = 0.0f;
    #pragma unroll 8
    for (int k=0; k<H; k++){
        float zk = lane_bcast(z0,k), jk = lane_bcast(j0,k);
        float w = W1s[lane*65+k];
        a1 = fmaf(w,zk,a1); j1a = fmaf(w,jk,j1a);
    }
    float z1 = softplus_f(a1), s1 = sigmoid_f(a1);
    float j1 = s1 * j1a;
    ws[OFF_S1 + b*H + lane] = s1;

    // layer 2 (linear)
    const int m = (lane < MD) ? lane : 0;
    float x = b2s[m], xd = 0.0f;
    #pragma unroll 8
    for (int k=0; k<H; k++){
        float zk = lane_bcast(z1,k), jk = lane_bcast(j1,k);
        float w = W2s[m*65+k];
        x = fmaf(w,zk,x); xd = fmaf(w,jk,xd);
    }
    if (lane < MD){ ws[OFF_X + b*MD + lane] = x; ws[OFF_XD + b*MD + lane] = xd; }
}

// ---------------- K2: per-lane 7x7 eigen + Loewner contractions ----------------
__global__ __launch_bounds__(64) void k2_eigen(
    const float* __restrict__ dq, const float* __restrict__ tau,
    float* __restrict__ ws)
{
    const int b = blockIdx.x*64 + threadIdx.x;

    float Ad[NQ], Ao[21], V[49];
    #pragma unroll
    for (int i=0;i<NQ;i++) Ad[i] = ws[OFF_X + b*MD + i];
    #pragma unroll
    for (int t=0;t<21;t++) Ao[t] = ws[OFF_X + b*MD + NQ + t];
    #pragma unroll
    for (int t=0;t<49;t++) V[t] = 0.0f;
    #pragma unroll
    for (int i=0;i<NQ;i++) V[i*7+i] = 1.0f;

    #pragma unroll 1
    for (int sweep=0; sweep<6; sweep++){
        #pragma unroll
        for (int p=0;p<6;p++){
            #pragma unroll
            for (int qq=p+1;qq<7;qq++){
                float app=Ad[p], aqq=Ad[qq], apq=Ao[OIDX(qq,p)];
                bool rot = fabsf(apq) > 1e-20f;
                float apq_s = rot ? apq : 1.0f;
                float theta = (aqq-app) / (2.0f*apq_s);
                float t = 1.0f/(fabsf(theta)+sqrtf(fmaf(theta,theta,1.0f)));
                t = (theta<0.0f)? -t : t;
                t = rot ? t : 0.0f;
                float c = rsqrtf(fmaf(t,t,1.0f));
                float s = t*c;
                #pragma unroll
                for (int j=0;j<7;j++){
                    if (j==p || j==qq) continue;
                    float ajp = (j<p)?  Ao[OIDX(p,j)]  : Ao[OIDX(j,p)];
                    float ajq = (j<qq)? Ao[OIDX(qq,j)] : Ao[OIDX(j,qq)];
                    float np_ = fmaf(c,ajp,-s*ajq);
                    float nq_ = fmaf(s,ajp, c*ajq);
                    if (j<p)  Ao[OIDX(p,j)]  = np_; else Ao[OIDX(j,p)]  = np_;
                    if (j<qq) Ao[OIDX(qq,j)] = nq_; else Ao[OIDX(j,qq)] = nq_;
                }
                Ad[p]  = fmaf(-t,apq,app);
                Ad[qq] = fmaf( t,apq,aqq);
                Ao[OIDX(qq,p)] = 0.0f;
                #pragma unroll
                for (int j=0;j<7;j++){
                    float vp=V[j*7+p], vq=V[j*7+qq];
                    V[j*7+p]  = fmaf(c,vp,-s*vq);
                    V[j*7+qq] = fmaf(s,vp, c*vq);
                }
            }
        }
    }

    float ee[7], iee[7];
    #pragma unroll
    for (int i=0;i<7;i++){ ee[i] = __expf(Ad[i]); iee[i] = 1.0f/ee[i]; }

    // Loewner off-diagonals
    float Ro[21];
    #pragma unroll
    for (int p=0;p<6;p++){
        #pragma unroll
        for (int qj=p+1;qj<7;qj++){
            float d = Ad[p]-Ad[qj];
            bool big = fabsf(d) > 1e-3f;
            float den = big ? d : 1.0f;
            float exact = (ee[p]-ee[qj])/den;
            float ser = sqrtf(ee[p]*ee[qj]) * fmaf(d*d, (1.0f/24.0f), 1.0f);
            Ro[OIDX(qj,p)] = big ? exact : ser;
        }
    }

    float dqv[7], tv[7];
    #pragma unroll
    for (int d=0;d<7;d++){ dqv[d] = dq[b*7+d]; tv[d] = tau[b*7+d]; }

    // w = V^T dq
    float w[7];
    #pragma unroll
    for (int a=0;a<7;a++){
        float acc = 0.0f;
        #pragma unroll
        for (int j=0;j<7;j++) acc = fmaf(V[j*7+a], dqv[j], acc);
        w[a] = acc;
    }

    // Y = R o (w w^T)
    float Yd[7], Yo[21];
    #pragma unroll
    for (int a=0;a<7;a++) Yd[a] = ee[a]*w[a]*w[a];
    #pragma unroll
    for (int p=0;p<6;p++){
        #pragma unroll
        for (int qj=p+1;qj<7;qj++) Yo[OIDX(qj,p)] = Ro[OIDX(qj,p)]*w[p]*w[qj];
    }

    // P = V * Y ; S = P * V^T (sym) -> sv
    float P[49];
    #pragma unroll
    for (int i=0;i<7;i++){
        #pragma unroll
        for (int a=0;a<7;a++){
            float acc = 0.0f;
            #pragma unroll
            for (int c=0;c<7;c++){
                float y = (c==a)? Yd[a] : ((c<a)? Yo[OIDX(a,c)] : Yo[OIDX(c,a)]);
                acc = fmaf(V[i*7+c], y, acc);
            }
            P[i*7+a] = acc;
        }
    }
    #pragma unroll
    for (int i=0;i<7;i++){
        #pragma unroll
        for (int j=i;j<7;j++){
            float acc = 0.0f;
            #pragma unroll
            for (int a=0;a<7;a++) acc = fmaf(P[i*7+a], V[j*7+a], acc);
            if (i==j) ws[OFF_SV + b*MD + i] = acc;
            else      ws[OFF_SV + b*MD + NQ + OIDX(j,i)] = 2.0f*acc;
        }
    }

    // Udot from xdot
    float Udd[7], Udo[21];
    #pragma unroll
    for (int i=0;i<7;i++)  Udd[i] = ws[OFF_XD + b*MD + i];
    #pragma unroll
    for (int t=0;t<21;t++) Udo[t] = ws[OFF_XD + b*MD + NQ + t];

    // P2 = Udot * V ; T = V^T P2 (sym)
    float P2[49];
    #pragma unroll
    for (int i=0;i<7;i++){
        #pragma unroll
        for (int a=0;a<7;a++){
            float acc = 0.0f;
            #pragma unroll
            for (int j=0;j<7;j++){
                float u = (i==j)? Udd[i] : ((j<i)? Udo[OIDX(i,j)] : Udo[OIDX(j,i)]);
                acc = fmaf(u, V[j*7+a], acc);
            }
            P2[i*7+a] = acc;
        }
    }
    float Td[7], To[21];
    #pragma unroll
    for (int a=0;a<7;a++){
        float acc = 0.0f;
        #pragma unroll
        for (int i=0;i<7;i++) acc = fmaf(V[i*7+a], P2[i*7+a], acc);
        Td[a] = acc;
    }
    #pragma unroll
    for (int a=0;a<6;a++){
        #pragma unroll
        for (int bb=a+1;bb<7;bb++){
            float acc = 0.0f;
            #pragma unroll
            for (int i=0;i<7;i++) acc = fmaf(V[i*7+a], P2[i*7+bb], acc);
            To[OIDX(bb,a)] = acc;
        }
    }

    // zw = (R o T) w ; u1 = V zw
    float zw[7];
    #pragma unroll
    for (int a=0;a<7;a++){
        float acc = ee[a]*Td[a]*w[a];
        #pragma unroll
        for (int bb=0;bb<7;bb++){
            if (bb==a) continue;
            float z = (bb<a)? (Ro[OIDX(a,bb)]*To[OIDX(a,bb)]) : (Ro[OIDX(bb,a)]*To[OIDX(bb,a)]);
            acc = fmaf(z, w[bb], acc);
        }
        zw[a] = acc;
    }
    float u1[7];
    #pragma unroll
    for (int i=0;i<7;i++){
        float acc = 0.0f;
        #pragma unroll
        for (int a=0;a<7;a++) acc = fmaf(V[i*7+a], zw[a], acc);
        u1[i] = acc;
    }

    // Minv = V diag(1/ee) V^T (sym)
    #pragma unroll
    for (int i=0;i<7;i++){
        #pragma unroll
        for (int j=i;j<7;j++){
            float acc = 0.0f;
            #pragma unroll
            for (int a=0;a<7;a++) acc = fmaf(V[i*7+a]*iee[a], V[j*7+a], acc);
            if (i==j) ws[OFF_MI + b*MD + i] = acc;
            else      ws[OFF_MI + b*MD + NQ + OIDX(j,i)] = acc;
        }
    }

    #pragma unroll
    for (int d=0;d<7;d++) ws[OFF_RP + b*NQ + d] = tv[d] - u1[d];
}

// ---------------- K3: V-net (g), M-net reverse (s), rhs, solve ----------------
__global__ __launch_bounds__(256) void k3_final(
    const float* __restrict__ q,
    const float* __restrict__ WM0, const float* __restrict__ WM1, const float* __restrict__ WM2,
    const float* __restrict__ WV0, const float* __restrict__ bV0,
    const float* __restrict__ WV1, const float* __restrict__ bV1,
    const float* __restrict__ WV2,
    const float* __restrict__ wsr,
    float* __restrict__ out)
{
    __shared__ float W0s[H*NQ], WV0s[H*NQ];
    __shared__ float W1s[H*65], WV1s[H*65];
    __shared__ float W2s[MD*65];
    __shared__ float bV0s[H], bV1s[H], WV2s[H];
    const int tid = threadIdx.x;
    for (int t = tid; t < H*NQ; t += 256){ W0s[t] = WM0[t]; WV0s[t] = WV0[t]; }
    for (int t = tid; t < H*H;  t += 256){ W1s[(t>>6)*65 + (t&63)] = WM1[t]; WV1s[(t>>6)*65 + (t&63)] = WV1[t]; }
    for (int t = tid; t < MD*H; t += 256) W2s[(t>>6)*65 + (t&63)] = WM2[t];
    if (tid < H){ bV0s[tid]=bV0[tid]; bV1s[tid]=bV1[tid]; WV2s[tid]=WV2[tid]; }
    __syncthreads();

    const int lane = tid & 63;
    const int b = (blockIdx.x<<2) + (tid>>6);

    float qv[NQ];
    #pragma unroll
    for (int d=0; d<NQ; d++) qv[d]=q[b*NQ+d];

    // ---- V-net forward ----
    float av0 = bV0s[lane];
    #pragma unroll
    for (int d=0; d<NQ; d++) av0 = fmaf(WV0s[lane*NQ+d], qv[d], av0);
    float zv0 = softplus_f(av0), sv0 = sigmoid_f(av0);

    float av1 = bV1s[lane];
    #pragma unroll 8
    for (int k=0;k<H;k++) av1 = fmaf(WV1s[lane*65+k], lane_bcast(zv0,k), av1);
    float r1 = WV2s[lane] * sigmoid_f(av1);

    // ---- V-net reverse: r0 = sv0 * (WV1^T r1); g = WV0^T r0 ----
    float racc = 0.0f;
    #pragma unroll 8
    for (int k=0;k<H;k++) racc = fmaf(WV1s[k*65+lane], lane_bcast(r1,k), racc);
    float r0 = sv0 * racc;
    float gp[7];
    #pragma unroll
    for (int d=0;d<NQ;d++) gp[d] = r0 * WV0s[lane*NQ+d];

    // ---- M-net reverse with cotangent sv ----
    float svv = wsr[OFF_SV + b*MD + ((lane<MD)?lane:0)];
    float s1  = wsr[OFF_S1 + b*H + lane];
    float rr1 = 0.0f;
    #pragma unroll
    for (int m=0;m<MD;m++) rr1 = fmaf(W2s[m*65+lane], lane_bcast(svv,m), rr1);
    rr1 *= s1;
    float s0 = wsr[OFF_S0 + b*H + lane];
    float tacc = 0.0f;
    #pragma unroll 8
    for (int i=0;i<H;i++) tacc = fmaf(W1s[i*65+lane], lane_bcast(rr1,i), tacc);
    float tk = s0 * tacc;
    float sp[7];
    #pragma unroll
    for (int d=0;d<NQ;d++) sp[d] = tk * W0s[lane*NQ+d];

    // ---- wave reductions (g and s) ----
    #pragma unroll
    for (int d=0;d<NQ;d++){
        float gv = gp[d], sv_ = sp[d];
        #pragma unroll
        for (int off=1; off<64; off<<=1){
            gv  += __shfl_xor(gv,  off, 64);
            sv_ += __shfl_xor(sv_, off, 64);
        }
        gp[d]=gv; sp[d]=sv_;
    }

    // rhs = (tau - u1) + 0.5*s - g  (all lanes compute all 7)
    float rhs[7];
    #pragma unroll
    for (int d=0;d<NQ;d++)
        rhs[d] = wsr[OFF_RP + b*NQ + d] + 0.5f*sp[d] - gp[d];

    // ddq = Minv * rhs
    if (lane < NQ){
        float acc = 0.0f;
        #pragma unroll
        for (int j=0;j<NQ;j++){
            int idx = (j==lane)? lane
                    : (NQ + ((j>lane)? OIDX(j,lane) : OIDX(lane,j)));
            acc = fmaf(wsr[OFF_MI + b*MD + idx], rhs[j], acc);
        }
        out[b*NQ+lane] = acc;
    }
}

extern "C" void kernel_launch(void* const* d_in, const int* in_sizes, int n_in,
                              void* d_out, int out_size, void* d_ws, size_t ws_size,
                              hipStream_t stream) {
    const float* q   = (const float*)d_in[0];
    const float* dq  = (const float*)d_in[1];
    const float* tau = (const float*)d_in[2];
    const float* WM0 = (const float*)d_in[3];
    const float* bM0 = (const float*)d_in[4];
    const float* WM1 = (const float*)d_in[5];
    const float* bM1 = (const float*)d_in[6];
    const float* WM2 = (const float*)d_in[7];
    const float* bM2 = (const float*)d_in[8];
    const float* WV0 = (const float*)d_in[9];
    const float* bV0 = (const float*)d_in[10];
    const float* WV1 = (const float*)d_in[11];
    const float* bV1 = (const float*)d_in[12];
    const float* WV2 = (const float*)d_in[13];
    // d_in[14] = bV2: unused (V's value never feeds the output)
    float* ws  = (float*)d_ws;
    float* out = (float*)d_out;

    hipLaunchKernelGGL(k1_mnet, dim3(B_TOT/4), dim3(256), 0, stream,
                       q, dq, WM0, bM0, WM1, bM1, WM2, bM2, ws);
    hipLaunchKernelGGL(k2_eigen, dim3(B_TOT/64), dim3(64), 0, stream,
                       dq, tau, ws);
    hipLaunchKernelGGL(k3_final, dim3(B_TOT/4), dim3(256), 0, stream,
                       q, WM0, WM1, WM2, WV0, bV0, WV1, bV1, WV2, ws, out);
}

// Round 5
// 103.625 us; speedup vs baseline: 1.1333x; 1.1333x over previous
//
#include <hip/hip_runtime.h>

#define B_TOT 16384
#define NQ 7
#define H 64
#define MD 28
#define NGRP (B_TOT/4)      // 4096 element-groups of 4
#define PGRID 1024          // persistent grid: 4 blocks/CU, all resident

// ws layout (floats)
#define OFF_X  0
#define OFF_XD (B_TOT*MD)
#define OFF_S0 (2*B_TOT*MD)
#define OFF_S1 (OFF_S0 + B_TOT*H)
#define OFF_SV (OFF_S1 + B_TOT*H)
#define OFF_MI (OFF_SV + B_TOT*MD)
#define OFF_RP (OFF_MI + B_TOT*MD)

#define OIDX(hi,lo) ((hi)*((hi)-1)/2 + (lo))

__device__ __forceinline__ float lane_bcast(float v, int k) {
    return __int_as_float(__builtin_amdgcn_readlane(__float_as_int(v), k));
}
__device__ __forceinline__ float sigmoid_f(float a) {
    return 1.0f / (1.0f + __expf(-a));
}
__device__ __forceinline__ float softplus_f(float a) {
    return fmaxf(a, 0.0f) + log1pf(__expf(-fabsf(a)));
}

// ---------------- K1: M-net forward + directional derivative (persistent) ----------------
__global__ __launch_bounds__(256) void k1_mnet(
    const float* __restrict__ q, const float* __restrict__ dq,
    const float* __restrict__ WM0, const float* __restrict__ bM0,
    const float* __restrict__ WM1, const float* __restrict__ bM1,
    const float* __restrict__ WM2, const float* __restrict__ bM2,
    float* __restrict__ ws)
{
    __shared__ float W1s[H*65];   // 16640 B, row access W1s[o*65+k]
    __shared__ float W2s[MD*65];  //  7280 B, row access W2s[m*65+k]
    const int tid = threadIdx.x;
    for (int t = tid; t < H*H;  t += 256) W1s[(t>>6)*65 + (t&63)] = WM1[t];
    for (int t = tid; t < MD*H; t += 256) W2s[(t>>6)*65 + (t&63)] = WM2[t];

    const int lane = tid & 63;
    const int wid  = tid >> 6;
    // element-independent per-lane registers (no LDS, no per-iteration reload)
    float w0r[NQ];
    #pragma unroll
    for (int d=0; d<NQ; d++) w0r[d] = WM0[lane*NQ + d];
    const float b0r = bM0[lane];
    const float b1r = bM1[lane];
    const int   m   = (lane < MD) ? lane : 0;
    const float b2r = bM2[m];
    __syncthreads();

    for (int g = blockIdx.x; g < NGRP; g += PGRID) {
        const int b = g*4 + wid;

        float qv[NQ], dqv[NQ];
        #pragma unroll
        for (int d=0; d<NQ; d++){ qv[d]=q[b*NQ+d]; dqv[d]=dq[b*NQ+d]; }

        // layer 0
        float a0 = b0r, j0d = 0.0f;
        #pragma unroll
        for (int d=0; d<NQ; d++){ a0 = fmaf(w0r[d],qv[d],a0); j0d = fmaf(w0r[d],dqv[d],j0d); }
        float z0 = softplus_f(a0), s0 = sigmoid_f(a0);
        float j0 = s0 * j0d;
        ws[OFF_S0 + b*H + lane] = s0;

        // layer 1
        float a1 = b1r, j1a = 0.0f;
        #pragma unroll 8
        for (int k=0; k<H; k++){
            float zk = lane_bcast(z0,k), jk = lane_bcast(j0,k);
            float w = W1s[lane*65+k];
            a1 = fmaf(w,zk,a1); j1a = fmaf(w,jk,j1a);
        }
        float z1 = softplus_f(a1), s1 = sigmoid_f(a1);
        float j1 = s1 * j1a;
        ws[OFF_S1 + b*H + lane] = s1;

        // layer 2 (linear)
        float x = b2r, xd = 0.0f;
        #pragma unroll 8
        for (int k=0; k<H; k++){
            float zk = lane_bcast(z1,k), jk = lane_bcast(j1,k);
            float w = W2s[m*65+k];
            x = fmaf(w,zk,x); xd = fmaf(w,jk,xd);
        }
        if (lane < MD){ ws[OFF_X + b*MD + lane] = x; ws[OFF_XD + b*MD + lane] = xd; }
    }
}

// ---------------- K2: per-lane 7x7 eigen + Loewner contractions (unchanged) ----------------
__global__ __launch_bounds__(64) void k2_eigen(
    const float* __restrict__ dq, const float* __restrict__ tau,
    float* __restrict__ ws)
{
    const int b = blockIdx.x*64 + threadIdx.x;

    float Ad[NQ], Ao[21], V[49];
    #pragma unroll
    for (int i=0;i<NQ;i++) Ad[i] = ws[OFF_X + b*MD + i];
    #pragma unroll
    for (int t=0;t<21;t++) Ao[t] = ws[OFF_X + b*MD + NQ + t];
    #pragma unroll
    for (int t=0;t<49;t++) V[t] = 0.0f;
    #pragma unroll
    for (int i=0;i<NQ;i++) V[i*7+i] = 1.0f;

    #pragma unroll 1
    for (int sweep=0; sweep<6; sweep++){
        #pragma unroll
        for (int p=0;p<6;p++){
            #pragma unroll
            for (int qq=p+1;qq<7;qq++){
                float app=Ad[p], aqq=Ad[qq], apq=Ao[OIDX(qq,p)];
                bool rot = fabsf(apq) > 1e-20f;
                float apq_s = rot ? apq : 1.0f;
                float theta = (aqq-app) / (2.0f*apq_s);
                float t = 1.0f/(fabsf(theta)+sqrtf(fmaf(theta,theta,1.0f)));
                t = (theta<0.0f)? -t : t;
                t = rot ? t : 0.0f;
                float c = rsqrtf(fmaf(t,t,1.0f));
                float s = t*c;
                #pragma unroll
                for (int j=0;j<7;j++){
                    if (j==p || j==qq) continue;
                    float ajp = (j<p)?  Ao[OIDX(p,j)]  : Ao[OIDX(j,p)];
                    float ajq = (j<qq)? Ao[OIDX(qq,j)] : Ao[OIDX(j,qq)];
                    float np_ = fmaf(c,ajp,-s*ajq);
                    float nq_ = fmaf(s,ajp, c*ajq);
                    if (j<p)  Ao[OIDX(p,j)]  = np_; else Ao[OIDX(j,p)]  = np_;
                    if (j<qq) Ao[OIDX(qq,j)] = nq_; else Ao[OIDX(j,qq)] = nq_;
                }
                Ad[p]  = fmaf(-t,apq,app);
                Ad[qq] = fmaf( t,apq,aqq);
                Ao[OIDX(qq,p)] = 0.0f;
                #pragma unroll
                for (int j=0;j<7;j++){
                    float vp=V[j*7+p], vq=V[j*7+qq];
                    V[j*7+p]  = fmaf(c,vp,-s*vq);
                    V[j*7+qq] = fmaf(s,vp, c*vq);
                }
            }
        }
    }

    float ee[7], iee[7];
    #pragma unroll
    for (int i=0;i<7;i++){ ee[i] = __expf(Ad[i]); iee[i] = 1.0f/ee[i]; }

    float Ro[21];
    #pragma unroll
    for (int p=0;p<6;p++){
        #pragma unroll
        for (int qj=p+1;qj<7;qj++){
            float d = Ad[p]-Ad[qj];
            bool big = fabsf(d) > 1e-3f;
            float den = big ? d : 1.0f;
            float exact = (ee[p]-ee[qj])/den;
            float ser = sqrtf(ee[p]*ee[qj]) * fmaf(d*d, (1.0f/24.0f), 1.0f);
            Ro[OIDX(qj,p)] = big ? exact : ser;
        }
    }

    float dqv[7], tv[7];
    #pragma unroll
    for (int d=0;d<7;d++){ dqv[d] = dq[b*7+d]; tv[d] = tau[b*7+d]; }

    float w[7];
    #pragma unroll
    for (int a=0;a<7;a++){
        float acc = 0.0f;
        #pragma unroll
        for (int j=0;j<7;j++) acc = fmaf(V[j*7+a], dqv[j], acc);
        w[a] = acc;
    }

    float Yd[7], Yo[21];
    #pragma unroll
    for (int a=0;a<7;a++) Yd[a] = ee[a]*w[a]*w[a];
    #pragma unroll
    for (int p=0;p<6;p++){
        #pragma unroll
        for (int qj=p+1;qj<7;qj++) Yo[OIDX(qj,p)] = Ro[OIDX(qj,p)]*w[p]*w[qj];
    }

    float P[49];
    #pragma unroll
    for (int i=0;i<7;i++){
        #pragma unroll
        for (int a=0;a<7;a++){
            float acc = 0.0f;
            #pragma unroll
            for (int c=0;c<7;c++){
                float y = (c==a)? Yd[a] : ((c<a)? Yo[OIDX(a,c)] : Yo[OIDX(c,a)]);
                acc = fmaf(V[i*7+c], y, acc);
            }
            P[i*7+a] = acc;
        }
    }
    #pragma unroll
    for (int i=0;i<7;i++){
        #pragma unroll
        for (int j=i;j<7;j++){
            float acc = 0.0f;
            #pragma unroll
            for (int a=0;a<7;a++) acc = fmaf(P[i*7+a], V[j*7+a], acc);
            if (i==j) ws[OFF_SV + b*MD + i] = acc;
            else      ws[OFF_SV + b*MD + NQ + OIDX(j,i)] = 2.0f*acc;
        }
    }

    float Udd[7], Udo[21];
    #pragma unroll
    for (int i=0;i<7;i++)  Udd[i] = ws[OFF_XD + b*MD + i];
    #pragma unroll
    for (int t=0;t<21;t++) Udo[t] = ws[OFF_XD + b*MD + NQ + t];

    float P2[49];
    #pragma unroll
    for (int i=0;i<7;i++){
        #pragma unroll
        for (int a=0;a<7;a++){
            float acc = 0.0f;
            #pragma unroll
            for (int j=0;j<7;j++){
                float u = (i==j)? Udd[i] : ((j<i)? Udo[OIDX(i,j)] : Udo[OIDX(j,i)]);
                acc = fmaf(u, V[j*7+a], acc);
            }
            P2[i*7+a] = acc;
        }
    }
    float Td[7], To[21];
    #pragma unroll
    for (int a=0;a<7;a++){
        float acc = 0.0f;
        #pragma unroll
        for (int i=0;i<7;i++) acc = fmaf(V[i*7+a], P2[i*7+a], acc);
        Td[a] = acc;
    }
    #pragma unroll
    for (int a=0;a<6;a++){
        #pragma unroll
        for (int bb=a+1;bb<7;bb++){
            float acc = 0.0f;
            #pragma unroll
            for (int i=0;i<7;i++) acc = fmaf(V[i*7+a], P2[i*7+bb], acc);
            To[OIDX(bb,a)] = acc;
        }
    }

    float zw[7];
    #pragma unroll
    for (int a=0;a<7;a++){
        float acc = ee[a]*Td[a]*w[a];
        #pragma unroll
        for (int bb=0;bb<7;bb++){
            if (bb==a) continue;
            float z = (bb<a)? (Ro[OIDX(a,bb)]*To[OIDX(a,bb)]) : (Ro[OIDX(bb,a)]*To[OIDX(bb,a)]);
            acc = fmaf(z, w[bb], acc);
        }
        zw[a] = acc;
    }
    float u1[7];
    #pragma unroll
    for (int i=0;i<7;i++){
        float acc = 0.0f;
        #pragma unroll
        for (int a=0;a<7;a++) acc = fmaf(V[i*7+a], zw[a], acc);
        u1[i] = acc;
    }

    #pragma unroll
    for (int i=0;i<7;i++){
        #pragma unroll
        for (int j=i;j<7;j++){
            float acc = 0.0f;
            #pragma unroll
            for (int a=0;a<7;a++) acc = fmaf(V[i*7+a]*iee[a], V[j*7+a], acc);
            if (i==j) ws[OFF_MI + b*MD + i] = acc;
            else      ws[OFF_MI + b*MD + NQ + OIDX(j,i)] = acc;
        }
    }

    #pragma unroll
    for (int d=0;d<7;d++) ws[OFF_RP + b*NQ + d] = tv[d] - u1[d];
}

// ---------------- K3: V-net (g), M-net reverse (s), rhs, solve (persistent) ----------------
__global__ __launch_bounds__(256) void k3_final(
    const float* __restrict__ q,
    const float* __restrict__ WM0, const float* __restrict__ WM1, const float* __restrict__ WM2,
    const float* __restrict__ WV0, const float* __restrict__ bV0,
    const float* __restrict__ WV1, const float* __restrict__ bV1,
    const float* __restrict__ WV2,
    const float* __restrict__ wsr,
    float* __restrict__ out)
{
    __shared__ float WV1s[H*65];  // row access (fwd) + col access (rev)
    __shared__ float W1Ts[H*65];  // W1T[l][i] = W1[i][l]; row access = W1 column
    const int tid = threadIdx.x;
    for (int t = tid; t < H*H; t += 256){
        WV1s[(t>>6)*65 + (t&63)] = WV1[t];
        W1Ts[(t&63)*65 + (t>>6)] = WM1[t];
    }

    const int lane = tid & 63;
    const int wid  = tid >> 6;
    // element-independent per-lane registers
    float wv0r[NQ], w0r[NQ];
    #pragma unroll
    for (int d=0; d<NQ; d++){ wv0r[d] = WV0[lane*NQ+d]; w0r[d] = WM0[lane*NQ+d]; }
    const float bv0r = bV0[lane];
    const float bv1r = bV1[lane];
    const float wv2r = WV2[lane];
    float w2c[MD];                        // W2 column `lane`
    #pragma unroll
    for (int mm=0; mm<MD; mm++) w2c[mm] = WM2[mm*H + lane];
    __syncthreads();

    for (int g = blockIdx.x; g < NGRP; g += PGRID) {
        const int b = g*4 + wid;

        float qv[NQ];
        #pragma unroll
        for (int d=0; d<NQ; d++) qv[d]=q[b*NQ+d];

        // ---- V-net forward ----
        float av0 = bv0r;
        #pragma unroll
        for (int d=0; d<NQ; d++) av0 = fmaf(wv0r[d], qv[d], av0);
        float zv0 = softplus_f(av0), sv0 = sigmoid_f(av0);

        float av1 = bv1r;
        #pragma unroll 8
        for (int k=0;k<H;k++) av1 = fmaf(WV1s[lane*65+k], lane_bcast(zv0,k), av1);
        float r1 = wv2r * sigmoid_f(av1);

        // ---- V-net reverse ----
        float racc = 0.0f;
        #pragma unroll 8
        for (int k=0;k<H;k++) racc = fmaf(WV1s[k*65+lane], lane_bcast(r1,k), racc);
        float r0 = sv0 * racc;

        // ---- M-net reverse with cotangent sv ----
        float svv = wsr[OFF_SV + b*MD + ((lane<MD)?lane:0)];
        float s1  = wsr[OFF_S1 + b*H + lane];
        float rr1 = 0.0f;
        #pragma unroll
        for (int mm=0;mm<MD;mm++) rr1 = fmaf(w2c[mm], lane_bcast(svv,mm), rr1);
        rr1 *= s1;
        float s0 = wsr[OFF_S0 + b*H + lane];
        float tacc = 0.0f;
        #pragma unroll 8
        for (int i=0;i<H;i++) tacc = fmaf(W1Ts[lane*65+i], lane_bcast(rr1,i), tacc);
        float tk = s0 * tacc;

        // ---- combined wave reduction: h[d] = 0.5*s[d] - g[d] ----
        float hp[NQ];
        #pragma unroll
        for (int d=0;d<NQ;d++) hp[d] = 0.5f*tk*w0r[d] - r0*wv0r[d];
        #pragma unroll
        for (int d=0;d<NQ;d++){
            float hv = hp[d];
            #pragma unroll
            for (int off=1; off<64; off<<=1) hv += __shfl_xor(hv, off, 64);
            hp[d]=hv;
        }

        // rhs = (tau - u1) + h
        float rhs[NQ];
        #pragma unroll
        for (int d=0;d<NQ;d++)
            rhs[d] = wsr[OFF_RP + b*NQ + d] + hp[d];

        // ddq = Minv * rhs
        if (lane < NQ){
            float acc = 0.0f;
            #pragma unroll
            for (int j=0;j<NQ;j++){
                int idx = (j==lane)? lane
                        : (NQ + ((j>lane)? OIDX(j,lane) : OIDX(lane,j)));
                acc = fmaf(wsr[OFF_MI + b*MD + idx], rhs[j], acc);
            }
            out[b*NQ+lane] = acc;
        }
    }
}

extern "C" void kernel_launch(void* const* d_in, const int* in_sizes, int n_in,
                              void* d_out, int out_size, void* d_ws, size_t ws_size,
                              hipStream_t stream) {
    const float* q   = (const float*)d_in[0];
    const float* dq  = (const float*)d_in[1];
    const float* tau = (const float*)d_in[2];
    const float* WM0 = (const float*)d_in[3];
    const float* bM0 = (const float*)d_in[4];
    const float* WM1 = (const float*)d_in[5];
    const float* bM1 = (const float*)d_in[6];
    const float* WM2 = (const float*)d_in[7];
    const float* bM2 = (const float*)d_in[8];
    const float* WV0 = (const float*)d_in[9];
    const float* bV0 = (const float*)d_in[10];
    const float* WV1 = (const float*)d_in[11];
    const float* bV1 = (const float*)d_in[12];
    const float* WV2 = (const float*)d_in[13];
    float* ws  = (float*)d_ws;
    float* out = (float*)d_out;

    hipLaunchKernelGGL(k1_mnet, dim3(PGRID), dim3(256), 0, stream,
                       q, dq, WM0, bM0, WM1, bM1, WM2, bM2, ws);
    hipLaunchKernelGGL(k2_eigen, dim3(B_TOT/64), dim3(64), 0, stream,
                       dq, tau, ws);
    hipLaunchKernelGGL(k3_final, dim3(PGRID), dim3(256), 0, stream,
                       q, WM0, WM1, WM2, WV0, bV0, WV1, bV1, WV2, ws, out);
}